// Round 1
// baseline (552.877 us; speedup 1.0000x reference)
//
#include <hip/hip_runtime.h>

// ---------------------------------------------------------------------------
// Attention_49185965474367: B=4, N=1024, D=1024, H=16, DH=64, INNER=1024
//   q = x@Wq; k,v = split(x@Wkv); sim = qk^T*scale + rel; masked softmax;
//   out = (attn@v) @ Wo + bo
// Plan: bf16 MFMA for all matmuls (fp32 accum), flash-style attention.
// ---------------------------------------------------------------------------

#define NEGMAX 3.402823466e+38f

typedef short short8 __attribute__((ext_vector_type(8)));
typedef float f32x4 __attribute__((ext_vector_type(4)));

__device__ __forceinline__ unsigned short f2bf(float f) {
  unsigned int u = __float_as_uint(f);
  u += 0x7FFFu + ((u >> 16) & 1u);   // round-to-nearest-even
  return (unsigned short)(u >> 16);
}

// ---------------- cast kernels ---------------------------------------------
__global__ void cast_x_k(const float* __restrict__ x, unsigned short* __restrict__ xb) {
  int i = (blockIdx.x * 256 + threadIdx.x) * 4;
  float4 v = *(const float4*)(x + i);
  ushort4 o;
  o.x = f2bf(v.x); o.y = f2bf(v.y); o.z = f2bf(v.z); o.w = f2bf(v.w);
  *(ushort4*)(xb + i) = o;
}

// w3t[n][d] = W3[d][n], n in [0,3072): [Wq | Wkv]
__global__ void cast_w3t_k(const float* __restrict__ Wq, const float* __restrict__ Wkv,
                           unsigned short* __restrict__ w3t) {
  int t = blockIdx.x * 256 + threadIdx.x;   // 3072 * 256 threads
  int n = t >> 8;
  int d0 = (t & 255) * 4;
  for (int j = 0; j < 4; ++j) {
    int d = d0 + j;
    float v = (n < 1024) ? Wq[(size_t)d * 1024 + n]
                         : Wkv[(size_t)d * 2048 + (n - 1024)];
    w3t[(size_t)n * 1024 + d] = f2bf(v);
  }
}

__global__ void cast_wot_k(const float* __restrict__ Wo, unsigned short* __restrict__ wot) {
  int t = blockIdx.x * 256 + threadIdx.x;   // 1024 * 256 threads
  int n = t >> 8;
  int d0 = (t & 255) * 4;
  for (int j = 0; j < 4; ++j) {
    int d = d0 + j;
    wot[(size_t)n * 1024 + d] = f2bf(Wo[(size_t)d * 1024 + n]);
  }
}

// ---------------- GEMM: C[M,N] = A[M,K] @ Bt[N,K]^T  (bf16 in, fp32 acc) ---
// 128x128 tile, BK=32, 256 threads (4 waves), each wave 64x64 (4x4 mfma tiles)
// MODE 0: QKV projection epilogue (scatter q,k per-head; v transposed)
// MODE 1: out-projection epilogue (+bias, fp32 out)
template <int MODE>
__global__ __launch_bounds__(256) void gemm_bt_k(
    const unsigned short* __restrict__ A, const unsigned short* __restrict__ Bt,
    unsigned short* __restrict__ qws, unsigned short* __restrict__ kws,
    unsigned short* __restrict__ vtws,
    const float* __restrict__ bias, float* __restrict__ Cout) {
  constexpr int K = 1024;
  constexpr int NKB = K / 32;
  __shared__ alignas(16) unsigned short As[128 * 32];
  __shared__ alignas(16) unsigned short Bs[128 * 32];
  const int tid = threadIdx.x;
  const int lane = tid & 63, w = tid >> 6;
  const int quad = lane >> 4, lanelo = lane & 15;
  const int tRow = blockIdx.y * 128, tCol = blockIdx.x * 128;
  const int wr = (w >> 1) * 64, wc = (w & 1) * 64;
  const char* AgB = (const char*)(A + (size_t)tRow * K);
  const char* BgB = (const char*)(Bt + (size_t)tCol * K);
  const int c0 = tid, c1 = tid + 256;
  const size_t a0off = (size_t)(c0 >> 2) * 2048 + (c0 & 3) * 16;
  const size_t a1off = (size_t)(c1 >> 2) * 2048 + (c1 & 3) * 16;

  f32x4 acc[4][4];
#pragma unroll
  for (int i = 0; i < 4; ++i)
#pragma unroll
    for (int j = 0; j < 4; ++j) acc[i][j] = (f32x4){0.f, 0.f, 0.f, 0.f};

  int4 ra0 = *(const int4*)(AgB + a0off);
  int4 ra1 = *(const int4*)(AgB + a1off);
  int4 rb0 = *(const int4*)(BgB + a0off);
  int4 rb1 = *(const int4*)(BgB + a1off);

  for (int kb = 0; kb < NKB; ++kb) {
    __syncthreads();
    *(int4*)((char*)As + c0 * 16) = ra0;
    *(int4*)((char*)As + c1 * 16) = ra1;
    *(int4*)((char*)Bs + c0 * 16) = rb0;
    *(int4*)((char*)Bs + c1 * 16) = rb1;
    __syncthreads();
    if (kb + 1 < NKB) {
      const size_t ko = (size_t)(kb + 1) * 64;
      ra0 = *(const int4*)(AgB + a0off + ko);
      ra1 = *(const int4*)(AgB + a1off + ko);
      rb0 = *(const int4*)(BgB + a0off + ko);
      rb1 = *(const int4*)(BgB + a1off + ko);
    }
    short8 af[4], bf[4];
#pragma unroll
    for (int i = 0; i < 4; ++i)
      af[i] = *(const short8*)(As + (wr + i * 16 + lanelo) * 32 + quad * 8);
#pragma unroll
    for (int j = 0; j < 4; ++j)
      bf[j] = *(const short8*)(Bs + (wc + j * 16 + lanelo) * 32 + quad * 8);
#pragma unroll
    for (int i = 0; i < 4; ++i)
#pragma unroll
      for (int j = 0; j < 4; ++j)
        acc[i][j] = __builtin_amdgcn_mfma_f32_16x16x32_bf16(af[i], bf[j], acc[i][j], 0, 0, 0);
  }

  // epilogue: C row = tRow + wr + i*16 + quad*4 + r ; col = tCol + wc + j*16 + lanelo
  if (MODE == 0) {
#pragma unroll
    for (int i = 0; i < 4; ++i) {
      int row = tRow + wr + i * 16 + quad * 4;  // row..row+3 (same 1024-block)
      int b_ = row >> 10;
      int npos = row & 1023;
#pragma unroll
      for (int j = 0; j < 4; ++j) {
        int col = tCol + wc + j * 16 + lanelo;
        if (col < 2048) {
          unsigned short* dst = (col < 1024) ? qws : kws;
          int c = col & 1023;
          int hh = c >> 6, dh = c & 63;
          size_t base = ((size_t)(b_ * 16 + hh) * 1024 + npos) * 64 + dh;
#pragma unroll
          for (int r = 0; r < 4; ++r) dst[base + (size_t)r * 64] = f2bf(acc[i][j][r]);
        } else {
          int c = col - 2048;
          ushort4 pk;
          pk.x = f2bf(acc[i][j][0]);
          pk.y = f2bf(acc[i][j][1]);
          pk.z = f2bf(acc[i][j][2]);
          pk.w = f2bf(acc[i][j][3]);
          *(ushort4*)&vtws[((size_t)(b_ * 16 + (c >> 6)) * 64 + (c & 63)) * 1024 + npos] = pk;
        }
      }
    }
  } else {
#pragma unroll
    for (int i = 0; i < 4; ++i) {
      int row = tRow + wr + i * 16 + quad * 4;
#pragma unroll
      for (int j = 0; j < 4; ++j) {
        int col = tCol + wc + j * 16 + lanelo;
        float bv = bias[col];
#pragma unroll
        for (int r = 0; r < 4; ++r)
          Cout[(size_t)(row + r) * 1024 + col] = acc[i][j][r] + bv;
      }
    }
  }
}

// ---------------- flash attention ------------------------------------------
// grid (16, 64): x = q-block of 64 rows, y = bh. 256 thr = 4 waves x 16 q-rows.
// q,k: bf16 [bh][n][64]; vt: bf16 [bh][dh][n]; rel fp32 [bh][n][n].
__global__ __launch_bounds__(256) void attn_k(
    const unsigned short* __restrict__ q_ws, const unsigned short* __restrict__ k_ws,
    const unsigned short* __restrict__ vt_ws, const float* __restrict__ rel,
    const int* __restrict__ qmask, const int* __restrict__ cmask,
    unsigned short* __restrict__ aout) {
  constexpr float SCALE = 0.125f;  // 64^-0.5
  __shared__ alignas(16) unsigned short Kl[32 * 72];  // rows padded: 144B stride
  __shared__ alignas(16) unsigned short Vl[64 * 40];  // rows padded: 80B stride
  __shared__ alignas(16) unsigned short Pl[4 * 16 * 40];
  __shared__ float cml[1024];

  const int tid = threadIdx.x;
  const int w = tid >> 6, lane = tid & 63;
  const int quad = lane >> 4, lanelo = lane & 15;
  const int bh = blockIdx.y, b_ = bh >> 4, h = bh & 15;
  const int qrow0 = blockIdx.x * 64 + w * 16;

  for (int i = tid; i < 1024; i += 256)
    cml[i] = (cmask[b_ * 1024 + i] != 0) ? 1.f : 0.f;

  const unsigned short* qg = q_ws + ((size_t)bh * 1024 + qrow0) * 64;
  short8 qf0 = *(const short8*)(qg + (size_t)lanelo * 64 + quad * 8);
  short8 qf1 = *(const short8*)(qg + (size_t)lanelo * 64 + 32 + quad * 8);

  float qmv[4];
#pragma unroll
  for (int r = 0; r < 4; ++r)
    qmv[r] = (qmask[b_ * 1024 + qrow0 + quad * 4 + r] != 0) ? 1.f : 0.f;

  f32x4 o[4];
#pragma unroll
  for (int g = 0; g < 4; ++g) o[g] = (f32x4){0.f, 0.f, 0.f, 0.f};
  float m_run[4], l_run[4];
#pragma unroll
  for (int r = 0; r < 4; ++r) { m_run[r] = -NEGMAX; l_run[r] = 0.f; }

  const char* kgB = (const char*)(k_ws + (size_t)bh * 65536);
  const char* vgB = (const char*)(vt_ws + (size_t)bh * 65536);
  const float* relg = rel + ((size_t)bh * 1024 + qrow0) * 1024;
  unsigned short* pw = Pl + w * 640;  // 16 rows x 40 shorts

  int4 kc = *(const int4*)(kgB + (size_t)(tid >> 3) * 128 + (tid & 7) * 16);
  int4 vc = *(const int4*)(vgB + (size_t)(tid >> 2) * 2048 + (tid & 3) * 16);

  for (int kb = 0; kb < 32; ++kb) {
    __syncthreads();
    *(int4*)((char*)Kl + (tid >> 3) * 144 + (tid & 7) * 16) = kc;
    *(int4*)((char*)Vl + (tid >> 2) * 80 + (tid & 3) * 16) = vc;
    __syncthreads();
    if (kb + 1 < 32) {
      kc = *(const int4*)(kgB + (size_t)((kb + 1) * 32 + (tid >> 3)) * 128 + (tid & 7) * 16);
      vc = *(const int4*)(vgB + (size_t)(tid >> 2) * 2048 + (size_t)(kb + 1) * 64 + (tid & 3) * 16);
    }

    // S = Q K^T for 16 q-rows x 32 keys (two 16x16 tiles)
    f32x4 s0 = (f32x4){0.f, 0.f, 0.f, 0.f}, s1 = s0;
    {
      short8 kf;
      kf = *(const short8*)((const char*)Kl + lanelo * 144 + quad * 16);
      s0 = __builtin_amdgcn_mfma_f32_16x16x32_bf16(qf0, kf, s0, 0, 0, 0);
      kf = *(const short8*)((const char*)Kl + lanelo * 144 + 64 + quad * 16);
      s0 = __builtin_amdgcn_mfma_f32_16x16x32_bf16(qf1, kf, s0, 0, 0, 0);
      kf = *(const short8*)((const char*)Kl + (16 + lanelo) * 144 + quad * 16);
      s1 = __builtin_amdgcn_mfma_f32_16x16x32_bf16(qf0, kf, s1, 0, 0, 0);
      kf = *(const short8*)((const char*)Kl + (16 + lanelo) * 144 + 64 + quad * 16);
      s1 = __builtin_amdgcn_mfma_f32_16x16x32_bf16(qf1, kf, s1, 0, 0, 0);
    }

    const int key0 = kb * 32 + lanelo;
    const float cm0 = cml[key0 & 1023], cm1 = cml[(key0 + 16) & 1023];
    float sv[2][4];
#pragma unroll
    for (int r = 0; r < 4; ++r) {
      const float* rrow = relg + (size_t)(quad * 4 + r) * 1024;
      float x0 = s0[r] * SCALE + rrow[key0];
      float x1 = s1[r] * SCALE + rrow[key0 + 16];
      bool qok = qmv[r] != 0.f;
      sv[0][r] = (qok && cm0 != 0.f) ? x0 : -NEGMAX;
      sv[1][r] = (qok && cm1 != 0.f) ? x1 : -NEGMAX;
    }

    // online softmax (row stats across the 16 lanes of each quad)
#pragma unroll
    for (int r = 0; r < 4; ++r) {
      float mloc = fmaxf(sv[0][r], sv[1][r]);
      for (int off = 1; off < 16; off <<= 1) mloc = fmaxf(mloc, __shfl_xor(mloc, off));
      float mnew = fmaxf(m_run[r], mloc);
      float alpha = __expf(m_run[r] - mnew);
      m_run[r] = mnew;
      float p0 = __expf(sv[0][r] - mnew);
      float p1 = __expf(sv[1][r] - mnew);
      float ps = p0 + p1;
      for (int off = 1; off < 16; off <<= 1) ps += __shfl_xor(ps, off);
      l_run[r] = l_run[r] * alpha + ps;
#pragma unroll
      for (int g = 0; g < 4; ++g) o[g][r] *= alpha;
      pw[(quad * 4 + r) * 40 + lanelo] = f2bf(p0);
      pw[(quad * 4 + r) * 40 + 16 + lanelo] = f2bf(p1);
    }

    // P (A-layout via LDS transpose) @ V
    short8 pa = *(const short8*)(pw + lanelo * 40 + quad * 8);
#pragma unroll
    for (int g = 0; g < 4; ++g) {
      short8 vb = *(const short8*)((const char*)Vl + (g * 16 + lanelo) * 80 + quad * 16);
      o[g] = __builtin_amdgcn_mfma_f32_16x16x32_bf16(pa, vb, o[g], 0, 0, 0);
    }
  }

#pragma unroll
  for (int r = 0; r < 4; ++r) {
    float inv = 1.f / l_run[r];
    size_t row = (size_t)(b_ * 1024 + qrow0 + quad * 4 + r) * 1024;
#pragma unroll
    for (int g = 0; g < 4; ++g)
      aout[row + h * 64 + g * 16 + lanelo] = f2bf(o[g][r] * inv);
  }
}

// ---------------- launch ----------------------------------------------------
extern "C" void kernel_launch(void* const* d_in, const int* in_sizes, int n_in,
                              void* d_out, int out_size, void* d_ws, size_t ws_size,
                              hipStream_t stream) {
  const float* x = (const float*)d_in[0];
  const float* rel = (const float*)d_in[1];
  const int* qmask = (const int*)d_in[2];
  const int* cmask = (const int*)d_in[3];
  const float* Wq = (const float*)d_in[4];
  const float* Wkv = (const float*)d_in[5];
  const float* Wo = (const float*)d_in[6];
  const float* bo = (const float*)d_in[7];
  float* out = (float*)d_out;

  char* ws = (char*)d_ws;
  const size_t MB = 1024 * 1024;
  unsigned short* w3t = (unsigned short*)(ws);            // 3072x1024 bf16 (6 MB)
  unsigned short* wot = (unsigned short*)(ws + 6 * MB);   // 1024x1024 bf16 (2 MB)
  unsigned short* xb  = (unsigned short*)(ws + 8 * MB);   // 4096x1024 bf16 (8 MB)
  unsigned short* qws = (unsigned short*)(ws + 16 * MB);  // 64x1024x64 (8 MB)
  unsigned short* kws = (unsigned short*)(ws + 24 * MB);  // 8 MB
  unsigned short* vtws = (unsigned short*)(ws + 32 * MB); // 8 MB, [bh][dh][n]
  unsigned short* aout = xb;  // reuse: x no longer needed after QKV GEMM

  cast_x_k<<<4096, 256, 0, stream>>>(x, xb);
  cast_w3t_k<<<3072, 256, 0, stream>>>(Wq, Wkv, w3t);
  cast_wot_k<<<1024, 256, 0, stream>>>(Wo, wot);
  gemm_bt_k<0><<<dim3(24, 32), 256, 0, stream>>>(xb, w3t, qws, kws, vtws, nullptr, nullptr);
  attn_k<<<dim3(16, 64), 256, 0, stream>>>(qws, kws, vtws, rel, qmask, cmask, aout);
  gemm_bt_k<1><<<dim3(8, 32), 256, 0, stream>>>(aout, wot, nullptr, nullptr, nullptr, bo, out);
}

// Round 2
// 493.872 us; speedup vs baseline: 1.1195x; 1.1195x over previous
//
#include <hip/hip_runtime.h>

// ---------------------------------------------------------------------------
// Attention_49185965474367: B=4, N=1024, D=1024, H=16, DH=64, INNER=1024
// R2: attn K-step 64 + rel/K/V register prefetch; GEMMs use global_load_lds;
//     weight transposes via LDS-tiled coalesced transpose-cast.
// ---------------------------------------------------------------------------

#define NEGMAX 3.402823466e+38f

typedef short short8 __attribute__((ext_vector_type(8)));
typedef float f32x4 __attribute__((ext_vector_type(4)));

__device__ __forceinline__ unsigned short f2bf(float f) {
  unsigned int u = __float_as_uint(f);
  u += 0x7FFFu + ((u >> 16) & 1u);   // round-to-nearest-even
  return (unsigned short)(u >> 16);
}

// async global->LDS, 16B per lane. lds_base must be wave-uniform; HW scatters
// lane i to lds_base + i*16 (guide §5; padding-free layouts only).
__device__ __forceinline__ void stage16(const void* g, void* lds_base, int lane) {
#if __has_builtin(__builtin_amdgcn_global_load_lds)
  __builtin_amdgcn_global_load_lds(
      (const __attribute__((address_space(1))) unsigned int*)g,
      (__attribute__((address_space(3))) unsigned int*)lds_base, 16, 0, 0);
#else
  *(int4*)((char*)lds_base + lane * 16) = *(const int4*)g;
#endif
}

// ---------------- cast kernels ---------------------------------------------
__global__ void cast_x_k(const float* __restrict__ x, unsigned short* __restrict__ xb) {
  int i = (blockIdx.x * 256 + threadIdx.x) * 4;
  float4 v = *(const float4*)(x + i);
  ushort4 o;
  o.x = f2bf(v.x); o.y = f2bf(v.y); o.z = f2bf(v.z); o.w = f2bf(v.w);
  *(ushort4*)(xb + i) = o;
}

// dst[n][d] = src[d][n]  (src fp32 [1024 x ldsrc], dst bf16 rows of 1024)
__global__ __launch_bounds__(256) void tcast_k(const float* __restrict__ src, int ldsrc,
                                               unsigned short* __restrict__ dst) {
  __shared__ float T[64][65];
  const int n0 = blockIdx.x * 64, d0 = blockIdx.y * 64;
  const int tx = threadIdx.x & 63, ty = threadIdx.x >> 6;
#pragma unroll
  for (int k = 0; k < 16; ++k) {
    int dl = k * 4 + ty;
    T[dl][tx] = src[(size_t)(d0 + dl) * ldsrc + n0 + tx];
  }
  __syncthreads();
#pragma unroll
  for (int k = 0; k < 16; ++k) {
    int nl = k * 4 + ty;
    dst[(size_t)(n0 + nl) * 1024 + d0 + tx] = f2bf(T[tx][nl]);
  }
}

// ---------------- GEMM: C[M,N] = A[M,K] @ Bt[N,K]^T  (bf16 in, fp32 acc) ---
// 128x128 tile, BK=32, 256 threads (4 waves), global_load_lds staging (m97).
template <int MODE>
__global__ __launch_bounds__(256) void gemm_bt_k(
    const unsigned short* __restrict__ A, const unsigned short* __restrict__ Bt,
    unsigned short* __restrict__ qws, unsigned short* __restrict__ kws,
    unsigned short* __restrict__ vtws,
    const float* __restrict__ bias, float* __restrict__ Cout) {
  constexpr int K = 1024;
  constexpr int NKB = K / 32;
  __shared__ alignas(16) unsigned short As[128 * 32];
  __shared__ alignas(16) unsigned short Bs[128 * 32];
  const int tid = threadIdx.x;
  const int lane = tid & 63, w = tid >> 6;
  const int quad = lane >> 4, lanelo = lane & 15;
  const int tRow = blockIdx.y * 128, tCol = blockIdx.x * 128;
  const int wr = (w >> 1) * 64, wc = (w & 1) * 64;
  const char* AgB = (const char*)(A + (size_t)tRow * K);
  const char* BgB = (const char*)(Bt + (size_t)tCol * K);
  const int c0 = tid, c1 = tid + 256;
  const size_t a0off = (size_t)(c0 >> 2) * 2048 + (c0 & 3) * 16;
  const size_t a1off = (size_t)(c1 >> 2) * 2048 + (c1 & 3) * 16;
  char* ldsA0 = (char*)As + w * 1024;
  char* ldsA1 = (char*)As + 4096 + w * 1024;
  char* ldsB0 = (char*)Bs + w * 1024;
  char* ldsB1 = (char*)Bs + 4096 + w * 1024;

  f32x4 acc[4][4];
#pragma unroll
  for (int i = 0; i < 4; ++i)
#pragma unroll
    for (int j = 0; j < 4; ++j) acc[i][j] = (f32x4){0.f, 0.f, 0.f, 0.f};

  for (int kb = 0; kb < NKB; ++kb) {
    if (kb) __syncthreads();
    const size_t ko = (size_t)kb * 64;
    stage16(AgB + a0off + ko, ldsA0, lane);
    stage16(AgB + a1off + ko, ldsA1, lane);
    stage16(BgB + a0off + ko, ldsB0, lane);
    stage16(BgB + a1off + ko, ldsB1, lane);
    __syncthreads();   // drains vmcnt before any frag read

    short8 af[4], bf[4];
#pragma unroll
    for (int i = 0; i < 4; ++i)
      af[i] = *(const short8*)(As + (wr + i * 16 + lanelo) * 32 + quad * 8);
#pragma unroll
    for (int j = 0; j < 4; ++j)
      bf[j] = *(const short8*)(Bs + (wc + j * 16 + lanelo) * 32 + quad * 8);
#pragma unroll
    for (int i = 0; i < 4; ++i)
#pragma unroll
      for (int j = 0; j < 4; ++j)
        acc[i][j] = __builtin_amdgcn_mfma_f32_16x16x32_bf16(af[i], bf[j], acc[i][j], 0, 0, 0);
  }

  if (MODE == 0) {
#pragma unroll
    for (int i = 0; i < 4; ++i) {
      int row = tRow + wr + i * 16 + quad * 4;
      int b_ = row >> 10;
      int npos = row & 1023;
#pragma unroll
      for (int j = 0; j < 4; ++j) {
        int col = tCol + wc + j * 16 + lanelo;
        if (col < 2048) {
          unsigned short* dst = (col < 1024) ? qws : kws;
          int c = col & 1023;
          int hh = c >> 6, dh = c & 63;
          size_t base = ((size_t)(b_ * 16 + hh) * 1024 + npos) * 64 + dh;
#pragma unroll
          for (int r = 0; r < 4; ++r) dst[base + (size_t)r * 64] = f2bf(acc[i][j][r]);
        } else {
          int c = col - 2048;
          ushort4 pk;
          pk.x = f2bf(acc[i][j][0]);
          pk.y = f2bf(acc[i][j][1]);
          pk.z = f2bf(acc[i][j][2]);
          pk.w = f2bf(acc[i][j][3]);
          *(ushort4*)&vtws[((size_t)(b_ * 16 + (c >> 6)) * 64 + (c & 63)) * 1024 + npos] = pk;
        }
      }
    }
  } else {
#pragma unroll
    for (int i = 0; i < 4; ++i) {
      int row = tRow + wr + i * 16 + quad * 4;
#pragma unroll
      for (int j = 0; j < 4; ++j) {
        int col = tCol + wc + j * 16 + lanelo;
        float bv = bias[col];
#pragma unroll
        for (int r = 0; r < 4; ++r)
          Cout[(size_t)(row + r) * 1024 + col] = acc[i][j][r] + bv;
      }
    }
  }
}

// ---------------- flash attention, K-step 64 -------------------------------
// grid (16, 64): x = 64 q-rows, y = bh. 256 thr = 4 waves x 16 q-rows.
// q,k: bf16 [bh][n][64]; vt: bf16 [bh][dh][n]; rel fp32 [bh][n][n].
__global__ __launch_bounds__(256) void attn_k(
    const unsigned short* __restrict__ q_ws, const unsigned short* __restrict__ k_ws,
    const unsigned short* __restrict__ vt_ws, const float* __restrict__ rel,
    const int* __restrict__ qmask, const int* __restrict__ cmask,
    unsigned short* __restrict__ aout) {
  constexpr float SCALE = 0.125f;  // 64^-0.5
  __shared__ alignas(16) unsigned short Kl[64 * 72];    // rows 144B (padded)
  __shared__ alignas(16) unsigned short Vl[64 * 72];    // [dh][64 keys + pad]
  __shared__ alignas(16) unsigned short Pl[4 * 16 * 72];
  __shared__ float cml[1024];

  const int tid = threadIdx.x;
  const int w = tid >> 6, lane = tid & 63;
  const int quad = lane >> 4, lanelo = lane & 15;
  const int bh = blockIdx.y, b_ = bh >> 4, h = bh & 15;
  const int qrow0 = blockIdx.x * 64 + w * 16;

  for (int i = tid; i < 1024; i += 256)
    cml[i] = (cmask[b_ * 1024 + i] != 0) ? 1.f : 0.f;

  const unsigned short* qg = q_ws + ((size_t)bh * 1024 + qrow0) * 64;
  short8 qf0 = *(const short8*)(qg + (size_t)lanelo * 64 + quad * 8);
  short8 qf1 = *(const short8*)(qg + (size_t)lanelo * 64 + 32 + quad * 8);

  float qmv[4];
#pragma unroll
  for (int r = 0; r < 4; ++r)
    qmv[r] = (qmask[b_ * 1024 + qrow0 + quad * 4 + r] != 0) ? 1.f : 0.f;

  f32x4 o[4];
#pragma unroll
  for (int g = 0; g < 4; ++g) o[g] = (f32x4){0.f, 0.f, 0.f, 0.f};
  float m_run[4], l_run[4];
#pragma unroll
  for (int r = 0; r < 4; ++r) { m_run[r] = -NEGMAX; l_run[r] = 0.f; }

  const char* kgB = (const char*)(k_ws + (size_t)bh * 65536);
  const char* vgB = (const char*)(vt_ws + (size_t)bh * 65536);
  const float* relg = rel + ((size_t)bh * 1024 + qrow0) * 1024;
  unsigned short* pw = Pl + w * 16 * 72;

  // staging: c = {tid, tid+256}; key/dh = c>>3 (0..63), 16B chunk = c&7
  const int k0 = tid >> 3, ch0 = tid & 7;
  int4 kc0 = *(const int4*)(kgB + (size_t)k0 * 128 + ch0 * 16);
  int4 kc1 = *(const int4*)(kgB + (size_t)(k0 + 32) * 128 + ch0 * 16);
  int4 vc0 = *(const int4*)(vgB + (size_t)k0 * 2048 + ch0 * 16);
  int4 vc1 = *(const int4*)(vgB + (size_t)(k0 + 32) * 2048 + ch0 * 16);

  // rel prefetch for kb=0 (keys c*16+lanelo)
  float rl[4][4];
#pragma unroll
  for (int r = 0; r < 4; ++r)
#pragma unroll
    for (int c = 0; c < 4; ++c)
      rl[r][c] = relg[(size_t)(quad * 4 + r) * 1024 + c * 16 + lanelo];

  for (int kb = 0; kb < 16; ++kb) {
    __syncthreads();
    *(int4*)((char*)Kl + k0 * 144 + ch0 * 16) = kc0;
    *(int4*)((char*)Kl + (k0 + 32) * 144 + ch0 * 16) = kc1;
    *(int4*)((char*)Vl + k0 * 144 + ch0 * 16) = vc0;
    *(int4*)((char*)Vl + (k0 + 32) * 144 + ch0 * 16) = vc1;
    __syncthreads();
    if (kb + 1 < 16) {
      const size_t kof = (size_t)(kb + 1) * 64;
      kc0 = *(const int4*)(kgB + (kof + k0) * 128 + ch0 * 16);
      kc1 = *(const int4*)(kgB + (kof + k0 + 32) * 128 + ch0 * 16);
      vc0 = *(const int4*)(vgB + (size_t)k0 * 2048 + kof * 2 + ch0 * 16);
      vc1 = *(const int4*)(vgB + (size_t)(k0 + 32) * 2048 + kof * 2 + ch0 * 16);
    }

    // S = Q K^T : 16 q-rows x 64 keys (4 key-groups of 16)
    f32x4 s[4];
#pragma unroll
    for (int c = 0; c < 4; ++c) {
      s[c] = (f32x4){0.f, 0.f, 0.f, 0.f};
      short8 kfa = *(const short8*)((const char*)Kl + (c * 16 + lanelo) * 144 + quad * 16);
      s[c] = __builtin_amdgcn_mfma_f32_16x16x32_bf16(qf0, kfa, s[c], 0, 0, 0);
      short8 kfb = *(const short8*)((const char*)Kl + (c * 16 + lanelo) * 144 + 64 + quad * 16);
      s[c] = __builtin_amdgcn_mfma_f32_16x16x32_bf16(qf1, kfb, s[c], 0, 0, 0);
    }

    // prefetch next iteration's rel while MFMAs / softmax run
    float rln[4][4];
    if (kb + 1 < 16) {
#pragma unroll
      for (int r = 0; r < 4; ++r)
#pragma unroll
        for (int c = 0; c < 4; ++c)
          rln[r][c] = relg[(size_t)(quad * 4 + r) * 1024 + (kb + 1) * 64 + c * 16 + lanelo];
    }

    float cm[4];
#pragma unroll
    for (int c = 0; c < 4; ++c) cm[c] = cml[kb * 64 + c * 16 + lanelo];

#pragma unroll
    for (int r = 0; r < 4; ++r) {
      const bool qok = qmv[r] != 0.f;
      float x[4], mloc = -NEGMAX;
#pragma unroll
      for (int c = 0; c < 4; ++c) {
        x[c] = (qok && cm[c] != 0.f) ? s[c][r] * SCALE + rl[r][c] : -NEGMAX;
        mloc = fmaxf(mloc, x[c]);
      }
      for (int off = 1; off < 16; off <<= 1) mloc = fmaxf(mloc, __shfl_xor(mloc, off));
      float mnew = fmaxf(m_run[r], mloc);
      float alpha = __expf(m_run[r] - mnew);
      m_run[r] = mnew;
      float ps = 0.f;
      unsigned short pb[4];
#pragma unroll
      for (int c = 0; c < 4; ++c) {
        float p = __expf(x[c] - mnew);
        ps += p;
        pb[c] = f2bf(p);
      }
      for (int off = 1; off < 16; off <<= 1) ps += __shfl_xor(ps, off);
      l_run[r] = l_run[r] * alpha + ps;
#pragma unroll
      for (int g = 0; g < 4; ++g) o[g][r] *= alpha;
#pragma unroll
      for (int c = 0; c < 4; ++c) pw[(quad * 4 + r) * 72 + c * 16 + lanelo] = pb[c];
    }

    if (kb + 1 < 16) {
#pragma unroll
      for (int r = 0; r < 4; ++r)
#pragma unroll
        for (int c = 0; c < 4; ++c) rl[r][c] = rln[r][c];
    }

    // P (A-layout via per-wave LDS transpose) @ V, two k=32 chunks
#pragma unroll
    for (int c2 = 0; c2 < 2; ++c2) {
      short8 pa = *(const short8*)((const char*)pw + lanelo * 144 + c2 * 64 + quad * 16);
#pragma unroll
      for (int g = 0; g < 4; ++g) {
        short8 vb = *(const short8*)((const char*)Vl + (g * 16 + lanelo) * 144 + c2 * 64 + quad * 16);
        o[g] = __builtin_amdgcn_mfma_f32_16x16x32_bf16(pa, vb, o[g], 0, 0, 0);
      }
    }
  }

#pragma unroll
  for (int r = 0; r < 4; ++r) {
    float inv = 1.f / l_run[r];
    size_t row = (size_t)(b_ * 1024 + qrow0 + quad * 4 + r) * 1024;
#pragma unroll
    for (int g = 0; g < 4; ++g)
      aout[row + h * 64 + g * 16 + lanelo] = f2bf(o[g][r] * inv);
  }
}

// ---------------- launch ----------------------------------------------------
extern "C" void kernel_launch(void* const* d_in, const int* in_sizes, int n_in,
                              void* d_out, int out_size, void* d_ws, size_t ws_size,
                              hipStream_t stream) {
  const float* x = (const float*)d_in[0];
  const float* rel = (const float*)d_in[1];
  const int* qmask = (const int*)d_in[2];
  const int* cmask = (const int*)d_in[3];
  const float* Wq = (const float*)d_in[4];
  const float* Wkv = (const float*)d_in[5];
  const float* Wo = (const float*)d_in[6];
  const float* bo = (const float*)d_in[7];
  float* out = (float*)d_out;

  char* ws = (char*)d_ws;
  const size_t MB = 1024 * 1024;
  unsigned short* w3t = (unsigned short*)(ws);            // 3072x1024 bf16 (6 MB)
  unsigned short* wot = (unsigned short*)(ws + 6 * MB);   // 1024x1024 bf16 (2 MB)
  unsigned short* xb  = (unsigned short*)(ws + 8 * MB);   // 4096x1024 bf16 (8 MB)
  unsigned short* qws = (unsigned short*)(ws + 16 * MB);  // [bh][n][64] (8 MB)
  unsigned short* kws = (unsigned short*)(ws + 24 * MB);  // 8 MB
  unsigned short* vtws = (unsigned short*)(ws + 32 * MB); // [bh][dh][n] (8 MB)
  unsigned short* aout = xb;  // reuse: x dead after QKV GEMM

  cast_x_k<<<4096, 256, 0, stream>>>(x, xb);
  tcast_k<<<dim3(16, 16), 256, 0, stream>>>(Wq, 1024, w3t);
  tcast_k<<<dim3(32, 16), 256, 0, stream>>>(Wkv, 2048, w3t + (size_t)1024 * 1024);
  tcast_k<<<dim3(16, 16), 256, 0, stream>>>(Wo, 1024, wot);
  gemm_bt_k<0><<<dim3(24, 32), 256, 0, stream>>>(xb, w3t, qws, kws, vtws, nullptr, nullptr);
  attn_k<<<dim3(16, 64), 256, 0, stream>>>(qws, kws, vtws, rel, qmask, cmask, aout);
  gemm_bt_k<1><<<dim3(8, 32), 256, 0, stream>>>(aout, wot, nullptr, nullptr, nullptr, bo, out);
}